// Round 2
// baseline (444.820 us; speedup 1.0000x reference)
//
#include <hip/hip_runtime.h>
#include <hip/hip_bf16.h>

typedef _Float16 half8_t __attribute__((ext_vector_type(8)));
typedef _Float16 half4_t __attribute__((ext_vector_type(4)));
typedef _Float16 half2_t __attribute__((ext_vector_type(2)));
typedef float float4_t __attribute__((ext_vector_type(4)));

// ---------------- radix-partition CSR build ----------------
// bucket b = dst >> SH (NBK <= 512). Edge chunks of CHUNK per workgroup.
// M[b*WG + w] = #edges of chunk w landing in bucket b; after k_colscan it is
// the per-chunk exclusive offset within bucket b. All hot counters are LDS.

__global__ __launch_bounds__(256) void k_hist(const int* __restrict__ dst, int E, int SH,
                                              int NBK, int WG, int CH, int* __restrict__ M) {
    extern __shared__ int lh[];
    for (int i = threadIdx.x; i < NBK; i += 256) lh[i] = 0;
    __syncthreads();
    int wg = blockIdx.x;
    int e0 = wg * CH, e1 = min(E, e0 + CH);
    for (int e = e0 + threadIdx.x; e < e1; e += 256)
        atomicAdd(&lh[dst[e] >> SH], 1);
    __syncthreads();
    for (int i = threadIdx.x; i < NBK; i += 256) M[i * WG + wg] = lh[i];
}

__global__ __launch_bounds__(256) void k_colscan(int* __restrict__ M, int WG,
                                                 int* __restrict__ totals) {
    __shared__ int s[256];
    int b = blockIdx.x, t = threadIdx.x;
    int v = (t < WG) ? M[b * WG + t] : 0;
    s[t] = v;
    __syncthreads();
    for (int off = 1; off < 256; off <<= 1) {
        int u = (t >= off) ? s[t - off] : 0;
        __syncthreads();
        s[t] += u;
        __syncthreads();
    }
    if (t < WG) M[b * WG + t] = s[t] - v;   // exclusive within bucket
    if (t == 255) totals[b] = s[255];
}

__global__ __launch_bounds__(512) void k_bucketscan(const int* __restrict__ totals, int NBK,
                                                    int E, int* __restrict__ base) {
    __shared__ int s[512];
    int t = threadIdx.x;
    int v = (t < NBK) ? totals[t] : 0;
    s[t] = v;
    __syncthreads();
    for (int off = 1; off < 512; off <<= 1) {
        int u = (t >= off) ? s[t - off] : 0;
        __syncthreads();
        s[t] += u;
        __syncthreads();
    }
    if (t < NBK) base[t] = s[t] - v;
    if (t == 0) base[NBK] = E;
}

// pack: low 23 bits = src node, high 9 bits = dst - (b<<SH). Valid for N < 2^23, SH <= 9.
__global__ __launch_bounds__(256) void k_scatter(const int* __restrict__ src,
                                                 const int* __restrict__ dst, int E, int SH,
                                                 int NBK, int WG, int CH,
                                                 const int* __restrict__ M,
                                                 const int* __restrict__ base,
                                                 unsigned* __restrict__ ebuf) {
    extern __shared__ int cur[];
    int wg = blockIdx.x;
    for (int i = threadIdx.x; i < NBK; i += 256) cur[i] = base[i] + M[i * WG + wg];
    __syncthreads();
    int e0 = wg * CH, e1 = min(E, e0 + CH);
    for (int e = e0 + threadIdx.x; e < e1; e += 256) {
        int d = dst[e];
        int b = d >> SH;
        int pos = atomicAdd(&cur[b], 1);                 // LDS atomic, wg-private
        ebuf[pos] = (unsigned)src[e] | ((unsigned)(d - (b << SH)) << 23);
    }
}

// one wg per bucket: LDS degree histogram -> local pair-scan -> rp/dinv, then
// second ebuf pass writes colx (bucket-local window, LDS cursors).
// Idle-capacity side jobs (consumed only by later dispatches):
//   blocks 0..63:  Wt transpose slices;  block 64: gptr binary search;
//   blocks 65..96: psum zero;            block 97: sums zero.
__global__ __launch_bounds__(256) void k_cntfill(const unsigned* __restrict__ ebuf,
                                                 const int* __restrict__ base, int SH, int N,
                                                 int E, float* __restrict__ dinv,
                                                 int* __restrict__ rp, int* __restrict__ colx,
                                                 const float* __restrict__ W0,
                                                 const float* __restrict__ W1,
                                                 _Float16* __restrict__ Wt0,
                                                 _Float16* __restrict__ Wt1,
                                                 const int* __restrict__ batch, int G,
                                                 int* __restrict__ gptr,
                                                 float* __restrict__ psum,
                                                 float* __restrict__ sums) {
    __shared__ int h[512];
    __shared__ int cur[512];
    __shared__ int s[256];
    int b = blockIdx.x, t = threadIdx.x;

    // side jobs
    if (b < 64) {
        int idx = b * 256 + t;            // 16384 elements over 64 blocks
        int n = idx >> 7, k = idx & 127;
        Wt0[n * 128 + k] = (_Float16)W0[k * 128 + n];
        Wt1[n * 128 + k] = (_Float16)W1[k * 128 + n];
    } else if (b == 64) {
        if (t <= G) {
            int g = t;
            int lo = 0, hi = N;
            while (lo < hi) {
                int mid = (lo + hi) >> 1;
                if (batch[mid] < g) lo = mid + 1; else hi = mid;
            }
            gptr[g] = lo;
        }
    } else if (b < 97) {
        int i0 = (b - 65) * 512 + t;      // G*128 = 16384 floats over 32 blocks
        psum[i0] = 0.f;
        psum[i0 + 256] = 0.f;
    } else if (b == 97) {
        if (t < 256) { sums[t] = 0.f; sums[t + 256] = 0.f; }
    }

    // main cntfill work
    int n0 = b << SH;
    int nb = min(N - n0, 1 << SH);
    for (int i = t; i < nb; i += 256) h[i] = 0;
    __syncthreads();
    int e0 = base[b], e1 = base[b + 1];
    for (int e = e0 + t; e < e1; e += 256)
        atomicAdd(&h[ebuf[e] >> 23], 1);
    __syncthreads();
    int i0 = 2 * t, i1 = 2 * t + 1;
    int a0 = (i0 < nb) ? h[i0] : 0;
    int a1 = (i1 < nb) ? h[i1] : 0;
    int ps = a0 + a1;
    s[t] = ps;
    __syncthreads();
    for (int off = 1; off < 256; off <<= 1) {
        int u = (t >= off) ? s[t - off] : 0;
        __syncthreads();
        s[t] += u;
        __syncthreads();
    }
    int excl = s[t] - ps;
    if (i0 < nb) {
        int r0 = e0 + excl;
        cur[i0] = r0;
        rp[n0 + i0] = r0;
        dinv[n0 + i0] = rsqrtf((float)(a0 + 1));
    }
    if (i1 < nb) {
        int r1 = e0 + excl + a0;
        cur[i1] = r1;
        rp[n0 + i1] = r1;
        dinv[n0 + i1] = rsqrtf((float)(a1 + 1));
    }
    if (b == (int)gridDim.x - 1 && t == 0) rp[N] = E;
    __syncthreads();
    for (int e = e0 + t; e < e1; e += 256) {
        unsigned v = ebuf[e];
        int pos = atomicAdd(&cur[v >> 23], 1);           // LDS atomic, wg-private
        colx[pos] = (int)(v & 0x7FFFFFu);
    }
}

// ---------------- MFMA GEMM: out[row] = (act(X[row]) @ W) * dinv[row] (fp16 out) ----------------
// 4 waves/block, 16 rows/wave. A-frags direct from global; B = half8 from
// L1/L2-resident Wt[n][k]. C/D: col=lane&15, row=quad*4+reg.

__global__ __launch_bounds__(256) void k_gemmM(const float* __restrict__ X,
                                               const _Float16* __restrict__ Wt,
                                               const float* __restrict__ dinv,
                                               _Float16* __restrict__ out, int N) {
    int t = threadIdx.x;
    int wv = t >> 6, lane = t & 63;
    int m = lane & 15, quad = lane >> 4;
    int rowbase = blockIdx.x * 64 + wv * 16;
    int arow = rowbase + m;
    int arowc = (arow < N) ? arow : (N - 1);
    const float* xr = X + (size_t)arowc * 128;

    float4_t acc[8];
    #pragma unroll
    for (int i = 0; i < 8; i++) acc[i] = (float4_t){0.f, 0.f, 0.f, 0.f};

    #pragma unroll
    for (int kc = 0; kc < 4; kc++) {
        int k0 = kc * 32 + quad * 8;
        float4 xa = *(const float4*)(xr + k0);
        float4 xb = *(const float4*)(xr + k0 + 4);
        float xv[8] = {xa.x, xa.y, xa.z, xa.w, xb.x, xb.y, xb.z, xb.w};
        half8_t a;
        #pragma unroll
        for (int j = 0; j < 8; j++) a[j] = (_Float16)xv[j];
        #pragma unroll
        for (int nt = 0; nt < 8; nt++) {
            half8_t b = *(const half8_t*)(Wt + (size_t)(nt * 16 + m) * 128 + k0);
            acc[nt] = __builtin_amdgcn_mfma_f32_16x16x32_f16(a, b, acc[nt], 0, 0, 0);
        }
    }

    float dv[4];
    #pragma unroll
    for (int r = 0; r < 4; r++) {
        int row = rowbase + quad * 4 + r;
        dv[r] = dinv[(row < N) ? row : (N - 1)];
    }
    #pragma unroll
    for (int r = 0; r < 4; r++) {
        int row = rowbase + quad * 4 + r;
        if (row < N) {
            _Float16* o = out + (size_t)row * 128 + m;
            #pragma unroll
            for (int nt = 0; nt < 8; nt++)
                o[nt * 16] = (_Float16)(acc[nt][r] * dv[r]);
        }
    }
}

// fp16-input variant with BN+ReLU fused into A-frag loads (layer 2)
__global__ __launch_bounds__(256) void k_gemmM16(const _Float16* __restrict__ X,
                                                 const _Float16* __restrict__ Wt,
                                                 const float* __restrict__ scale,
                                                 const float* __restrict__ shift,
                                                 const float* __restrict__ dinv,
                                                 _Float16* __restrict__ out, int N) {
    int t = threadIdx.x;
    int wv = t >> 6, lane = t & 63;
    int m = lane & 15, quad = lane >> 4;
    int rowbase = blockIdx.x * 64 + wv * 16;
    int arow = rowbase + m;
    int arowc = (arow < N) ? arow : (N - 1);
    const _Float16* xr = X + (size_t)arowc * 128;

    float4_t acc[8];
    #pragma unroll
    for (int i = 0; i < 8; i++) acc[i] = (float4_t){0.f, 0.f, 0.f, 0.f};

    #pragma unroll
    for (int kc = 0; kc < 4; kc++) {
        int k0 = kc * 32 + quad * 8;
        half8_t x8 = *(const half8_t*)(xr + k0);
        float4 sa = *(const float4*)(scale + k0);
        float4 sb = *(const float4*)(scale + k0 + 4);
        float4 ha = *(const float4*)(shift + k0);
        float4 hb = *(const float4*)(shift + k0 + 4);
        float sv[8] = {sa.x, sa.y, sa.z, sa.w, sb.x, sb.y, sb.z, sb.w};
        float hv[8] = {ha.x, ha.y, ha.z, ha.w, hb.x, hb.y, hb.z, hb.w};
        half8_t a;
        #pragma unroll
        for (int j = 0; j < 8; j++)
            a[j] = (_Float16)fmaxf(fmaf((float)x8[j], sv[j], hv[j]), 0.f);
        #pragma unroll
        for (int nt = 0; nt < 8; nt++) {
            half8_t b = *(const half8_t*)(Wt + (size_t)(nt * 16 + m) * 128 + k0);
            acc[nt] = __builtin_amdgcn_mfma_f32_16x16x32_f16(a, b, acc[nt], 0, 0, 0);
        }
    }

    float dv[4];
    #pragma unroll
    for (int r = 0; r < 4; r++) {
        int row = rowbase + quad * 4 + r;
        dv[r] = dinv[(row < N) ? row : (N - 1)];
    }
    #pragma unroll
    for (int r = 0; r < 4; r++) {
        int row = rowbase + quad * 4 + r;
        if (row < N) {
            _Float16* o = out + (size_t)row * 128 + m;
            #pragma unroll
            for (int nt = 0; nt < 8; nt++)
                o[nt * 16] = (_Float16)(acc[nt][r] * dv[r]);
        }
    }
}

// ---------------- Aggregation: out[i] = dinv[i]*(hs[i] + sum_{j in in(i)} hs[j]) + b ----------------
// One wave per node. Quarter-wave row reads: 16 lanes x half8 (16 B) cover a
// 256 B row; the 4 quarters stream 4 independent edge slots. Degrees are
// ~Poisson(16): P(deg>32) ~ 1e-4, so almost every node is handled by ONE
// fully-predicated batch of 8 slots/quarter (32 gathers in flight per wave,
// invalid slots weight-0 via fmaf). This removes the serialized remainder
// loop that dominated the latency-bound profile. deg>32 falls back to the
// loop. Both branches are wave-uniform (deg is per-node).

__global__ __launch_bounds__(256) void k_agg(const _Float16* __restrict__ hs,
                                             const int* __restrict__ rp,
                                             const int* __restrict__ colx,
                                             const float* __restrict__ dinv,
                                             const float* __restrict__ bias,
                                             _Float16* __restrict__ out, int N) {
    int wave = (blockIdx.x * 256 + threadIdx.x) >> 6;
    int lane = threadIdx.x & 63;
    if (wave >= N) return;
    int i = wave;
    int q = lane >> 4;            // quarter 0..3: independent edge stream
    int c8 = lane & 15;           // channels 8*c8 .. 8*c8+7
    const half8_t* row8 = (const half8_t*)hs;

    half8_t sv = row8[(size_t)i * 16 + c8];   // self row, issued early
    int k0 = rp[i], k1 = rp[i + 1];
    int deg = k1 - k0;

    float a[8] = {0.f, 0.f, 0.f, 0.f, 0.f, 0.f, 0.f, 0.f};

    if (deg <= 32) {
        // one predicated batch: slots k0+q+4*s, s=0..7 covers deg<=32
        int safe = (deg > 0) ? k0 : 0;
        int j[8];
        float w[8];
        #pragma unroll
        for (int s2 = 0; s2 < 8; s2++) {
            int kk = k0 + q + 4 * s2;
            bool val = kk < k1;
            w[s2] = val ? 1.f : 0.f;
            j[s2] = colx[val ? kk : safe];
        }
        half8_t v[8];
        #pragma unroll
        for (int s2 = 0; s2 < 8; s2++)
            v[s2] = row8[(size_t)j[s2] * 16 + c8];
        #pragma unroll
        for (int s2 = 0; s2 < 8; s2++) {
            #pragma unroll
            for (int t = 0; t < 8; t++)
                a[t] = fmaf((float)v[s2][t], w[s2], a[t]);
        }
    } else {
        int k = k0 + q;
        for (; k + 12 < k1; k += 16) {
            int j0 = colx[k];
            int j1 = colx[k + 4];
            int j2 = colx[k + 8];
            int j3 = colx[k + 12];
            half8_t v0 = row8[(size_t)j0 * 16 + c8];
            half8_t v1 = row8[(size_t)j1 * 16 + c8];
            half8_t v2 = row8[(size_t)j2 * 16 + c8];
            half8_t v3 = row8[(size_t)j3 * 16 + c8];
            #pragma unroll
            for (int t = 0; t < 8; t++) a[t] += (float)v0[t];
            #pragma unroll
            for (int t = 0; t < 8; t++) a[t] += (float)v1[t];
            #pragma unroll
            for (int t = 0; t < 8; t++) a[t] += (float)v2[t];
            #pragma unroll
            for (int t = 0; t < 8; t++) a[t] += (float)v3[t];
        }
        for (; k < k1; k += 4) {
            int j = colx[k];
            half8_t v = row8[(size_t)j * 16 + c8];
            #pragma unroll
            for (int t = 0; t < 8; t++) a[t] += (float)v[t];
        }
    }

    // cross-quarter reduce: lanes {l, l+16, l+32, l+48} hold same channels
    #pragma unroll
    for (int t = 0; t < 8; t++) {
        float x = a[t];
        x += __shfl_xor(x, 16);
        x += __shfl_xor(x, 32);
        a[t] = x;
    }

    if (q == 0) {
        float d = dinv[i];
        float4 bA = ((const float4*)bias)[2 * c8];
        float4 bB = ((const float4*)bias)[2 * c8 + 1];
        float bb[8] = {bA.x, bA.y, bA.z, bA.w, bB.x, bB.y, bB.z, bB.w};
        half8_t o;
        #pragma unroll
        for (int t = 0; t < 8; t++)
            o[t] = (_Float16)fmaf(a[t] + (float)sv[t], d, bb[t]);
        ((half8_t*)out)[(size_t)i * 16 + c8] = o;
    }
}

// ---------------- BN stats (fp16 input) ----------------

__global__ __launch_bounds__(256) void k_stats(const _Float16* __restrict__ x, int N,
                                               float* __restrict__ sums) {
    int lane = threadIdx.x & 63;
    int wv = threadIdx.x >> 6;
    int gw = blockIdx.x * 4 + wv;
    int stride = gridDim.x * 4;
    const half2_t* b = (const half2_t*)x;
    float2 s = make_float2(0.f, 0.f), q = make_float2(0.f, 0.f);
    for (int i = gw; i < N; i += stride) {
        half2_t v = b[(size_t)i * 64 + lane];
        float vx = (float)v.x, vy = (float)v.y;
        s.x += vx; s.y += vy;
        q.x += vx * vx; q.y += vy * vy;
    }
    __shared__ float ls[4][128];
    __shared__ float lq[4][128];
    ls[wv][2 * lane] = s.x; ls[wv][2 * lane + 1] = s.y;
    lq[wv][2 * lane] = q.x; lq[wv][2 * lane + 1] = q.y;
    __syncthreads();
    int t = threadIdx.x;
    if (t < 128) {
        float ts = ls[0][t] + ls[1][t] + ls[2][t] + ls[3][t];
        float tq = lq[0][t] + lq[1][t] + lq[2][t] + lq[3][t];
        atomicAdd(&sums[t], ts);
        atomicAdd(&sums[128 + t], tq);
    }
}

__global__ void k_bnp(const float* __restrict__ sums, const float* __restrict__ g,
                      const float* __restrict__ be, int N, float* __restrict__ scale,
                      float* __restrict__ shift) {
    int c = threadIdx.x;
    if (c < 128) {
        float invN = 1.0f / (float)N;
        float mu = sums[c] * invN;
        float var = sums[128 + c] * invN - mu * mu;
        var = fmaxf(var, 0.f);
        float s = g[c] * rsqrtf(var + 1e-5f);
        scale[c] = s;
        shift[c] = fmaf(-mu, s, be[c]);
    }
}

// ---------------- Pooling: node-parallel, per-wave run flush (fp16 input) ----------------

__global__ __launch_bounds__(256) void k_pool2(const _Float16* __restrict__ x,
                                               const int* __restrict__ batch,
                                               const float* __restrict__ scale,
                                               const float* __restrict__ shift,
                                               float* __restrict__ psum, int N) {
    int nw = gridDim.x * 4;
    int w = blockIdx.x * 4 + (threadIdx.x >> 6);
    int lane = threadIdx.x & 63;
    int per = (N + nw - 1) / nw;
    int i0 = w * per, i1 = min(N, i0 + per);
    if (i0 >= i1) return;
    const half2_t* b = (const half2_t*)x;
    float2 s2 = ((const float2*)scale)[lane];
    float2 h2 = ((const float2*)shift)[lane];
    float2 acc = make_float2(0.f, 0.f);
    int g = batch[i0];
    for (int i = i0; i < i1; i++) {
        int gi = batch[i];
        if (gi != g) {   // wave-uniform branch
            atomicAdd(&psum[g * 128 + 2 * lane], acc.x);
            atomicAdd(&psum[g * 128 + 2 * lane + 1], acc.y);
            acc = make_float2(0.f, 0.f);
            g = gi;
        }
        half2_t v = b[(size_t)i * 64 + lane];
        acc.x += fmaxf(fmaf((float)v.x, s2.x, h2.x), 0.f);
        acc.y += fmaxf(fmaf((float)v.y, s2.y, h2.y), 0.f);
    }
    atomicAdd(&psum[g * 128 + 2 * lane], acc.x);
    atomicAdd(&psum[g * 128 + 2 * lane + 1], acc.y);
}

// ---------------- Head: out[g][o] = (psum[g]/cnt[g]) @ Wout[:,o] + bout[o] ----------------

__global__ __launch_bounds__(64) void k_final(const float* __restrict__ psum,
                                              const int* __restrict__ gptr,
                                              const float* __restrict__ Wout,
                                              const float* __restrict__ bout,
                                              float* __restrict__ out, int O) {
    int g = blockIdx.x, o = threadIdx.x;
    int cnt = gptr[g + 1] - gptr[g];
    float inv = 1.0f / fmaxf((float)cnt, 1.f);
    float acc = 0.f;
    for (int c = 0; c < 128; c++) acc = fmaf(psum[g * 128 + c], Wout[c * O + o], acc);
    out[g * O + o] = fmaf(acc, inv, bout[o]);
}

// ---------------- Host launch ----------------

extern "C" void kernel_launch(void* const* d_in, const int* in_sizes, int n_in,
                              void* d_out, int out_size, void* d_ws, size_t ws_size,
                              hipStream_t stream) {
    const float* x    = (const float*)d_in[0];
    const int*   edge = (const int*)d_in[1];
    const int*   batch= (const int*)d_in[2];
    const float* W0   = (const float*)d_in[4];
    const float* b0   = (const float*)d_in[5];
    const float* g0   = (const float*)d_in[6];
    const float* be0  = (const float*)d_in[7];
    const float* W1   = (const float*)d_in[8];
    const float* b1   = (const float*)d_in[9];
    const float* g1   = (const float*)d_in[10];
    const float* be1  = (const float*)d_in[11];
    const float* Wout = (const float*)d_in[12];
    const float* bout = (const float*)d_in[13];
    float* out = (float*)d_out;

    const int Hh  = in_sizes[5];              // 128
    const int Fin = in_sizes[4] / Hh;         // 128
    const int N   = in_sizes[0] / Fin;        // 100000
    const int E   = in_sizes[1] / 2;          // 1600000
    const int O   = in_sizes[13];             // 64
    const int G   = out_size / O;             // 128
    (void)Hh; (void)n_in; (void)ws_size;

    // bucket shift: smallest SH >= 8 with <= 512 buckets (pack needs SH <= 9, N < 2^23)
    int SH = 8;
    while (((N + (1 << SH) - 1) >> SH) > 512) SH++;
    const int NBK = (N + (1 << SH) - 1) >> SH;
    const int CH  = ((E + 255) / 256 > 8192) ? (E + 255) / 256 : 8192;  // chunk, keep WG<=256
    const int WG  = (E + CH - 1) / CH;

    char* p = (char*)d_ws;
    auto alloc = [&](size_t bytes) -> void* {
        void* r = (void*)p;
        p += (bytes + 255) & ~(size_t)255;
        return r;
    };
    _Float16* A   = (_Float16*)alloc((size_t)N * 128 * 2);   // fp16 gather table
    _Float16* B   = (_Float16*)alloc((size_t)N * 128 * 2);   // fp16 layer output
    float* dinv   = (float*)alloc((size_t)N * 4);
    int*   rp     = (int*)alloc((size_t)(N + 1) * 4);
    int*   colx   = (int*)alloc((size_t)E * 4);
    unsigned* ebuf= (unsigned*)alloc((size_t)E * 4);
    int*   M      = (int*)alloc((size_t)NBK * WG * 4);
    int*   totals = (int*)alloc((size_t)NBK * 4);
    int*   base   = (int*)alloc((size_t)(NBK + 1) * 4);
    float* sums   = (float*)alloc(512 * 4);   // [sum1|sq1|sum2|sq2]
    float* bn     = (float*)alloc(512 * 4);   // [scale1|shift1|scale2|shift2]
    int*   gptr   = (int*)alloc((size_t)(G + 1) * 4);
    float* psum   = (float*)alloc((size_t)G * 128 * 4);
    _Float16* Wt0 = (_Float16*)alloc(128 * 128 * 2);
    _Float16* Wt1 = (_Float16*)alloc(128 * 128 * 2);

    const int* src = edge;
    const int* dst = edge + E;

    // radix-partition CSR build; k_cntfill also does wprep/gptr/psum-zero/sums-zero
    k_hist<<<WG, 256, NBK * 4, stream>>>(dst, E, SH, NBK, WG, CH, M);
    k_colscan<<<NBK, 256, 0, stream>>>(M, WG, totals);
    k_bucketscan<<<1, 512, 0, stream>>>(totals, NBK, E, base);
    k_scatter<<<WG, 256, NBK * 4, stream>>>(src, dst, E, SH, NBK, WG, CH, M, base, ebuf);
    k_cntfill<<<NBK, 256, 0, stream>>>(ebuf, base, SH, N, E, dinv, rp, colx,
                                       W0, W1, Wt0, Wt1, batch, G, gptr, psum, sums);

    // Layer 1 (MFMA GEMM fp32 in)
    k_gemmM<<<(N + 63) / 64, 256, 0, stream>>>(x, Wt0, dinv, A, N);
    k_agg<<<(N + 3) / 4, 256, 0, stream>>>(A, rp, colx, dinv, b0, B, N);
    k_stats<<<512, 256, 0, stream>>>(B, N, sums);
    k_bnp<<<1, 128, 0, stream>>>(sums, g0, be0, N, bn, bn + 128);

    // Layer 2 (fp16 in, BN+ReLU fused into MFMA A-frag loads)
    k_gemmM16<<<(N + 63) / 64, 256, 0, stream>>>(B, Wt1, bn, bn + 128, dinv, A, N);
    k_agg<<<(N + 3) / 4, 256, 0, stream>>>(A, rp, colx, dinv, b1, B, N);
    k_stats<<<512, 256, 0, stream>>>(B, N, sums + 256);
    k_bnp<<<1, 128, 0, stream>>>(sums + 256, g1, be1, N, bn + 256, bn + 384);

    // Pool (BN+ReLU fused) + head (mean division fused)
    k_pool2<<<512, 256, 0, stream>>>(B, batch, bn + 256, bn + 384, psum, N);
    k_final<<<G, 64, 0, stream>>>(psum, gptr, Wout, bout, out, O);
}

// Round 4
// 436.913 us; speedup vs baseline: 1.0181x; 1.0181x over previous
//
#include <hip/hip_runtime.h>
#include <hip/hip_bf16.h>

typedef _Float16 half8_t __attribute__((ext_vector_type(8)));
typedef _Float16 half4_t __attribute__((ext_vector_type(4)));
typedef _Float16 half2_t __attribute__((ext_vector_type(2)));
typedef float float4_t __attribute__((ext_vector_type(4)));

// ---------------- radix-partition CSR build ----------------
// bucket b = dst >> SH (NBK <= 512). Edge chunks of CHUNK per workgroup.
// M[b*WG + w] = #edges of chunk w landing in bucket b; after k_colscan it is
// the per-chunk exclusive offset within bucket b. All hot counters are LDS.

__global__ __launch_bounds__(256) void k_hist(const int* __restrict__ dst, int E, int SH,
                                              int NBK, int WG, int CH, int* __restrict__ M) {
    extern __shared__ int lh[];
    for (int i = threadIdx.x; i < NBK; i += 256) lh[i] = 0;
    __syncthreads();
    int wg = blockIdx.x;
    int e0 = wg * CH, e1 = min(E, e0 + CH);
    for (int e = e0 + threadIdx.x; e < e1; e += 256)
        atomicAdd(&lh[dst[e] >> SH], 1);
    __syncthreads();
    for (int i = threadIdx.x; i < NBK; i += 256) M[i * WG + wg] = lh[i];
}

__global__ __launch_bounds__(256) void k_colscan(int* __restrict__ M, int WG,
                                                 int* __restrict__ totals) {
    __shared__ int s[256];
    int b = blockIdx.x, t = threadIdx.x;
    int v = (t < WG) ? M[b * WG + t] : 0;
    s[t] = v;
    __syncthreads();
    for (int off = 1; off < 256; off <<= 1) {
        int u = (t >= off) ? s[t - off] : 0;
        __syncthreads();
        s[t] += u;
        __syncthreads();
    }
    if (t < WG) M[b * WG + t] = s[t] - v;   // exclusive within bucket
    if (t == 255) totals[b] = s[255];
}

__global__ __launch_bounds__(512) void k_bucketscan(const int* __restrict__ totals, int NBK,
                                                    int E, int* __restrict__ base) {
    __shared__ int s[512];
    int t = threadIdx.x;
    int v = (t < NBK) ? totals[t] : 0;
    s[t] = v;
    __syncthreads();
    for (int off = 1; off < 512; off <<= 1) {
        int u = (t >= off) ? s[t - off] : 0;
        __syncthreads();
        s[t] += u;
        __syncthreads();
    }
    if (t < NBK) base[t] = s[t] - v;
    if (t == 0) base[NBK] = E;
}

// pack: low 23 bits = src node, high 9 bits = dst - (b<<SH). Valid for N < 2^23, SH <= 9.
__global__ __launch_bounds__(256) void k_scatter(const int* __restrict__ src,
                                                 const int* __restrict__ dst, int E, int SH,
                                                 int NBK, int WG, int CH,
                                                 const int* __restrict__ M,
                                                 const int* __restrict__ base,
                                                 unsigned* __restrict__ ebuf) {
    extern __shared__ int cur[];
    int wg = blockIdx.x;
    for (int i = threadIdx.x; i < NBK; i += 256) cur[i] = base[i] + M[i * WG + wg];
    __syncthreads();
    int e0 = wg * CH, e1 = min(E, e0 + CH);
    for (int e = e0 + threadIdx.x; e < e1; e += 256) {
        int d = dst[e];
        int b = d >> SH;
        int pos = atomicAdd(&cur[b], 1);                 // LDS atomic, wg-private
        ebuf[pos] = (unsigned)src[e] | ((unsigned)(d - (b << SH)) << 23);
    }
}

// one wg per bucket: LDS degree histogram -> local pair-scan -> rp/dinv, then
// second ebuf pass writes colx (bucket-local window, LDS cursors).
// Idle-capacity side jobs (consumed only by later dispatches):
//   blocks 0..63:  Wt transpose slices;  block 64: gptr binary search;
//   blocks 65..96: psum zero;            block 97: sums zero.
__global__ __launch_bounds__(256) void k_cntfill(const unsigned* __restrict__ ebuf,
                                                 const int* __restrict__ base, int SH, int N,
                                                 int E, float* __restrict__ dinv,
                                                 int* __restrict__ rp, int* __restrict__ colx,
                                                 const float* __restrict__ W0,
                                                 const float* __restrict__ W1,
                                                 _Float16* __restrict__ Wt0,
                                                 _Float16* __restrict__ Wt1,
                                                 const int* __restrict__ batch, int G,
                                                 int* __restrict__ gptr,
                                                 float* __restrict__ psum,
                                                 float* __restrict__ sums) {
    __shared__ int h[512];
    __shared__ int cur[512];
    __shared__ int s[256];
    int b = blockIdx.x, t = threadIdx.x;

    // side jobs
    if (b < 64) {
        int idx = b * 256 + t;            // 16384 elements over 64 blocks
        int n = idx >> 7, k = idx & 127;
        Wt0[n * 128 + k] = (_Float16)W0[k * 128 + n];
        Wt1[n * 128 + k] = (_Float16)W1[k * 128 + n];
    } else if (b == 64) {
        if (t <= G) {
            int g = t;
            int lo = 0, hi = N;
            while (lo < hi) {
                int mid = (lo + hi) >> 1;
                if (batch[mid] < g) lo = mid + 1; else hi = mid;
            }
            gptr[g] = lo;
        }
    } else if (b < 97) {
        int i0 = (b - 65) * 512 + t;      // G*128 = 16384 floats over 32 blocks
        psum[i0] = 0.f;
        psum[i0 + 256] = 0.f;
    } else if (b == 97) {
        if (t < 256) { sums[t] = 0.f; sums[t + 256] = 0.f; }
    }

    // main cntfill work
    int n0 = b << SH;
    int nb = min(N - n0, 1 << SH);
    for (int i = t; i < nb; i += 256) h[i] = 0;
    __syncthreads();
    int e0 = base[b], e1 = base[b + 1];
    for (int e = e0 + t; e < e1; e += 256)
        atomicAdd(&h[ebuf[e] >> 23], 1);
    __syncthreads();
    int i0 = 2 * t, i1 = 2 * t + 1;
    int a0 = (i0 < nb) ? h[i0] : 0;
    int a1 = (i1 < nb) ? h[i1] : 0;
    int ps = a0 + a1;
    s[t] = ps;
    __syncthreads();
    for (int off = 1; off < 256; off <<= 1) {
        int u = (t >= off) ? s[t - off] : 0;
        __syncthreads();
        s[t] += u;
        __syncthreads();
    }
    int excl = s[t] - ps;
    if (i0 < nb) {
        int r0 = e0 + excl;
        cur[i0] = r0;
        rp[n0 + i0] = r0;
        dinv[n0 + i0] = rsqrtf((float)(a0 + 1));
    }
    if (i1 < nb) {
        int r1 = e0 + excl + a0;
        cur[i1] = r1;
        rp[n0 + i1] = r1;
        dinv[n0 + i1] = rsqrtf((float)(a1 + 1));
    }
    if (b == (int)gridDim.x - 1 && t == 0) rp[N] = E;
    __syncthreads();
    for (int e = e0 + t; e < e1; e += 256) {
        unsigned v = ebuf[e];
        int pos = atomicAdd(&cur[v >> 23], 1);           // LDS atomic, wg-private
        colx[pos] = (int)(v & 0x7FFFFFu);
    }
}

// ---------------- MFMA GEMM layer 1: out = fp8((X@W)*dinv) ----------------
// 4 waves/block, 16 rows/wave. A-frags direct from global; B = half8 from
// L1/L2-resident Wt[n][k]. C/D: col=lane&15, row=quad*4+reg.
// fp8-e4m3 output halves the layer-1 gather table (12.8 MB: better L2
// residency, half the miss bytes in k_agg8).

__global__ __launch_bounds__(256) void k_gemmM(const float* __restrict__ X,
                                               const _Float16* __restrict__ Wt,
                                               const float* __restrict__ dinv,
                                               unsigned char* __restrict__ out, int N) {
    int t = threadIdx.x;
    int wv = t >> 6, lane = t & 63;
    int m = lane & 15, quad = lane >> 4;
    int rowbase = blockIdx.x * 64 + wv * 16;
    int arow = rowbase + m;
    int arowc = (arow < N) ? arow : (N - 1);
    const float* xr = X + (size_t)arowc * 128;

    float4_t acc[8];
    #pragma unroll
    for (int i = 0; i < 8; i++) acc[i] = (float4_t){0.f, 0.f, 0.f, 0.f};

    #pragma unroll
    for (int kc = 0; kc < 4; kc++) {
        int k0 = kc * 32 + quad * 8;
        float4 xa = *(const float4*)(xr + k0);
        float4 xb = *(const float4*)(xr + k0 + 4);
        float xv[8] = {xa.x, xa.y, xa.z, xa.w, xb.x, xb.y, xb.z, xb.w};
        half8_t a;
        #pragma unroll
        for (int j = 0; j < 8; j++) a[j] = (_Float16)xv[j];
        #pragma unroll
        for (int nt = 0; nt < 8; nt++) {
            half8_t b = *(const half8_t*)(Wt + (size_t)(nt * 16 + m) * 128 + k0);
            acc[nt] = __builtin_amdgcn_mfma_f32_16x16x32_f16(a, b, acc[nt], 0, 0, 0);
        }
    }

    float dv[4];
    #pragma unroll
    for (int r = 0; r < 4; r++) {
        int row = rowbase + quad * 4 + r;
        dv[r] = dinv[(row < N) ? row : (N - 1)];
    }
    #pragma unroll
    for (int r = 0; r < 4; r++) {
        int row = rowbase + quad * 4 + r;
        if (row < N) {
            unsigned char* o = out + (size_t)row * 128 + m;
            #pragma unroll
            for (int nt = 0; nt < 8; nt++) {
                float v = acc[nt][r] * dv[r];
                int pk = __builtin_amdgcn_cvt_pk_fp8_f32(v, v, 0, false);
                o[nt * 16] = (unsigned char)(pk & 0xFF);
            }
        }
    }
}

// fp16-input variant with BN+ReLU fused into A-frag loads (layer 2, fp16 out)
__global__ __launch_bounds__(256) void k_gemmM16(const _Float16* __restrict__ X,
                                                 const _Float16* __restrict__ Wt,
                                                 const float* __restrict__ scale,
                                                 const float* __restrict__ shift,
                                                 const float* __restrict__ dinv,
                                                 _Float16* __restrict__ out, int N) {
    int t = threadIdx.x;
    int wv = t >> 6, lane = t & 63;
    int m = lane & 15, quad = lane >> 4;
    int rowbase = blockIdx.x * 64 + wv * 16;
    int arow = rowbase + m;
    int arowc = (arow < N) ? arow : (N - 1);
    const _Float16* xr = X + (size_t)arowc * 128;

    float4_t acc[8];
    #pragma unroll
    for (int i = 0; i < 8; i++) acc[i] = (float4_t){0.f, 0.f, 0.f, 0.f};

    #pragma unroll
    for (int kc = 0; kc < 4; kc++) {
        int k0 = kc * 32 + quad * 8;
        half8_t x8 = *(const half8_t*)(xr + k0);
        float4 sa = *(const float4*)(scale + k0);
        float4 sb = *(const float4*)(scale + k0 + 4);
        float4 ha = *(const float4*)(shift + k0);
        float4 hb = *(const float4*)(shift + k0 + 4);
        float sv[8] = {sa.x, sa.y, sa.z, sa.w, sb.x, sb.y, sb.z, sb.w};
        float hv[8] = {ha.x, ha.y, ha.z, ha.w, hb.x, hb.y, hb.z, hb.w};
        half8_t a;
        #pragma unroll
        for (int j = 0; j < 8; j++)
            a[j] = (_Float16)fmaxf(fmaf((float)x8[j], sv[j], hv[j]), 0.f);
        #pragma unroll
        for (int nt = 0; nt < 8; nt++) {
            half8_t b = *(const half8_t*)(Wt + (size_t)(nt * 16 + m) * 128 + k0);
            acc[nt] = __builtin_amdgcn_mfma_f32_16x16x32_f16(a, b, acc[nt], 0, 0, 0);
        }
    }

    float dv[4];
    #pragma unroll
    for (int r = 0; r < 4; r++) {
        int row = rowbase + quad * 4 + r;
        dv[r] = dinv[(row < N) ? row : (N - 1)];
    }
    #pragma unroll
    for (int r = 0; r < 4; r++) {
        int row = rowbase + quad * 4 + r;
        if (row < N) {
            _Float16* o = out + (size_t)row * 128 + m;
            #pragma unroll
            for (int nt = 0; nt < 8; nt++)
                o[nt * 16] = (_Float16)(acc[nt][r] * dv[r]);
        }
    }
}

// ---------------- Aggregation (fp8 table, layer 1) ----------------
// out[i] = dinv[i]*(hs[i] + sum_j hs[j]) + b. One wave per node.
// Quarter-wave row reads: 16 lanes x 8B (8 fp8 ch) cover the 128B row;
// 4 quarters = 4 independent edge slots; one predicated batch of 8
// slots/quarter covers deg<=32 (P(deg>32) ~ 1e-4 for Poisson(16)).
// cvt_f32_fp8 byte-select must be a LITERAL -> f8x4 helper unrolls 0..3.

__device__ __forceinline__ void f8x4(unsigned w, float* o) {
    o[0] = __builtin_amdgcn_cvt_f32_fp8((int)w, 0);
    o[1] = __builtin_amdgcn_cvt_f32_fp8((int)w, 1);
    o[2] = __builtin_amdgcn_cvt_f32_fp8((int)w, 2);
    o[3] = __builtin_amdgcn_cvt_f32_fp8((int)w, 3);
}

__global__ __launch_bounds__(256) void k_agg8(const unsigned char* __restrict__ hs,
                                              const int* __restrict__ rp,
                                              const int* __restrict__ colx,
                                              const float* __restrict__ dinv,
                                              const float* __restrict__ bias,
                                              _Float16* __restrict__ out, int N) {
    int wave = (blockIdx.x * 256 + threadIdx.x) >> 6;
    int lane = threadIdx.x & 63;
    if (wave >= N) return;
    int i = wave;
    int q = lane >> 4;            // quarter 0..3: independent edge stream
    int c8 = lane & 15;           // channels 8*c8 .. 8*c8+7

    uint2 sw = *(const uint2*)(hs + (size_t)i * 128 + c8 * 8);   // self, early
    int k0 = rp[i], k1 = rp[i + 1];
    int deg = k1 - k0;

    float a[8] = {0.f, 0.f, 0.f, 0.f, 0.f, 0.f, 0.f, 0.f};

    if (deg <= 32) {
        int safe = (deg > 0) ? k0 : 0;
        int j[8];
        float w[8];
        #pragma unroll
        for (int s2 = 0; s2 < 8; s2++) {
            int kk = k0 + q + 4 * s2;
            bool val = kk < k1;
            w[s2] = val ? 1.f : 0.f;
            j[s2] = colx[val ? kk : safe];
        }
        uint2 v[8];
        #pragma unroll
        for (int s2 = 0; s2 < 8; s2++)
            v[s2] = *(const uint2*)(hs + (size_t)j[s2] * 128 + c8 * 8);
        #pragma unroll
        for (int s2 = 0; s2 < 8; s2++) {
            float f0[4], f1[4];
            f8x4(v[s2].x, f0);
            f8x4(v[s2].y, f1);
            #pragma unroll
            for (int b = 0; b < 4; b++) {
                a[b]     = fmaf(f0[b], w[s2], a[b]);
                a[4 + b] = fmaf(f1[b], w[s2], a[4 + b]);
            }
        }
    } else {
        int k = k0 + q;
        for (; k + 12 < k1; k += 16) {
            uint2 v0 = *(const uint2*)(hs + (size_t)colx[k] * 128 + c8 * 8);
            uint2 v1 = *(const uint2*)(hs + (size_t)colx[k + 4] * 128 + c8 * 8);
            uint2 v2 = *(const uint2*)(hs + (size_t)colx[k + 8] * 128 + c8 * 8);
            uint2 v3 = *(const uint2*)(hs + (size_t)colx[k + 12] * 128 + c8 * 8);
            float f0[4], f1[4];
            f8x4(v0.x, f0); f8x4(v0.y, f1);
            #pragma unroll
            for (int b = 0; b < 4; b++) { a[b] += f0[b]; a[4 + b] += f1[b]; }
            f8x4(v1.x, f0); f8x4(v1.y, f1);
            #pragma unroll
            for (int b = 0; b < 4; b++) { a[b] += f0[b]; a[4 + b] += f1[b]; }
            f8x4(v2.x, f0); f8x4(v2.y, f1);
            #pragma unroll
            for (int b = 0; b < 4; b++) { a[b] += f0[b]; a[4 + b] += f1[b]; }
            f8x4(v3.x, f0); f8x4(v3.y, f1);
            #pragma unroll
            for (int b = 0; b < 4; b++) { a[b] += f0[b]; a[4 + b] += f1[b]; }
        }
        for (; k < k1; k += 4) {
            uint2 v = *(const uint2*)(hs + (size_t)colx[k] * 128 + c8 * 8);
            float f0[4], f1[4];
            f8x4(v.x, f0); f8x4(v.y, f1);
            #pragma unroll
            for (int b = 0; b < 4; b++) { a[b] += f0[b]; a[4 + b] += f1[b]; }
        }
    }

    // cross-quarter reduce: lanes {l, l+16, l+32, l+48} hold same channels
    #pragma unroll
    for (int t = 0; t < 8; t++) {
        float x = a[t];
        x += __shfl_xor(x, 16);
        x += __shfl_xor(x, 32);
        a[t] = x;
    }

    if (q == 0) {
        float d = dinv[i];
        float4 bA = ((const float4*)bias)[2 * c8];
        float4 bB = ((const float4*)bias)[2 * c8 + 1];
        float bb[8] = {bA.x, bA.y, bA.z, bA.w, bB.x, bB.y, bB.z, bB.w};
        float sf[8];
        f8x4(sw.x, sf);
        f8x4(sw.y, sf + 4);
        half8_t o;
        #pragma unroll
        for (int t = 0; t < 8; t++)
            o[t] = (_Float16)fmaf(a[t] + sf[t], d, bb[t]);
        ((half8_t*)out)[(size_t)i * 16 + c8] = o;
    }
}

// ---------------- Aggregation (fp16 table, layer 2) ----------------

__global__ __launch_bounds__(256) void k_agg(const _Float16* __restrict__ hs,
                                             const int* __restrict__ rp,
                                             const int* __restrict__ colx,
                                             const float* __restrict__ dinv,
                                             const float* __restrict__ bias,
                                             _Float16* __restrict__ out, int N) {
    int wave = (blockIdx.x * 256 + threadIdx.x) >> 6;
    int lane = threadIdx.x & 63;
    if (wave >= N) return;
    int i = wave;
    int q = lane >> 4;            // quarter 0..3: independent edge stream
    int c8 = lane & 15;           // channels 8*c8 .. 8*c8+7
    const half8_t* row8 = (const half8_t*)hs;

    half8_t sv = row8[(size_t)i * 16 + c8];   // self row, issued early
    int k0 = rp[i], k1 = rp[i + 1];
    int deg = k1 - k0;

    float a[8] = {0.f, 0.f, 0.f, 0.f, 0.f, 0.f, 0.f, 0.f};

    if (deg <= 32) {
        int safe = (deg > 0) ? k0 : 0;
        int j[8];
        float w[8];
        #pragma unroll
        for (int s2 = 0; s2 < 8; s2++) {
            int kk = k0 + q + 4 * s2;
            bool val = kk < k1;
            w[s2] = val ? 1.f : 0.f;
            j[s2] = colx[val ? kk : safe];
        }
        half8_t v[8];
        #pragma unroll
        for (int s2 = 0; s2 < 8; s2++)
            v[s2] = row8[(size_t)j[s2] * 16 + c8];
        #pragma unroll
        for (int s2 = 0; s2 < 8; s2++) {
            #pragma unroll
            for (int t = 0; t < 8; t++)
                a[t] = fmaf((float)v[s2][t], w[s2], a[t]);
        }
    } else {
        int k = k0 + q;
        for (; k + 12 < k1; k += 16) {
            int j0 = colx[k];
            int j1 = colx[k + 4];
            int j2 = colx[k + 8];
            int j3 = colx[k + 12];
            half8_t v0 = row8[(size_t)j0 * 16 + c8];
            half8_t v1 = row8[(size_t)j1 * 16 + c8];
            half8_t v2 = row8[(size_t)j2 * 16 + c8];
            half8_t v3 = row8[(size_t)j3 * 16 + c8];
            #pragma unroll
            for (int t = 0; t < 8; t++) a[t] += (float)v0[t];
            #pragma unroll
            for (int t = 0; t < 8; t++) a[t] += (float)v1[t];
            #pragma unroll
            for (int t = 0; t < 8; t++) a[t] += (float)v2[t];
            #pragma unroll
            for (int t = 0; t < 8; t++) a[t] += (float)v3[t];
        }
        for (; k < k1; k += 4) {
            int j = colx[k];
            half8_t v = row8[(size_t)j * 16 + c8];
            #pragma unroll
            for (int t = 0; t < 8; t++) a[t] += (float)v[t];
        }
    }

    // cross-quarter reduce: lanes {l, l+16, l+32, l+48} hold same channels
    #pragma unroll
    for (int t = 0; t < 8; t++) {
        float x = a[t];
        x += __shfl_xor(x, 16);
        x += __shfl_xor(x, 32);
        a[t] = x;
    }

    if (q == 0) {
        float d = dinv[i];
        float4 bA = ((const float4*)bias)[2 * c8];
        float4 bB = ((const float4*)bias)[2 * c8 + 1];
        float bb[8] = {bA.x, bA.y, bA.z, bA.w, bB.x, bB.y, bB.z, bB.w};
        half8_t o;
        #pragma unroll
        for (int t = 0; t < 8; t++)
            o[t] = (_Float16)fmaf(a[t] + (float)sv[t], d, bb[t]);
        ((half8_t*)out)[(size_t)i * 16 + c8] = o;
    }
}

// ---------------- BN stats (fp16 input) ----------------

__global__ __launch_bounds__(256) void k_stats(const _Float16* __restrict__ x, int N,
                                               float* __restrict__ sums) {
    int lane = threadIdx.x & 63;
    int wv = threadIdx.x >> 6;
    int gw = blockIdx.x * 4 + wv;
    int stride = gridDim.x * 4;
    const half2_t* b = (const half2_t*)x;
    float2 s = make_float2(0.f, 0.f), q = make_float2(0.f, 0.f);
    for (int i = gw; i < N; i += stride) {
        half2_t v = b[(size_t)i * 64 + lane];
        float vx = (float)v.x, vy = (float)v.y;
        s.x += vx; s.y += vy;
        q.x += vx * vx; q.y += vy * vy;
    }
    __shared__ float ls[4][128];
    __shared__ float lq[4][128];
    ls[wv][2 * lane] = s.x; ls[wv][2 * lane + 1] = s.y;
    lq[wv][2 * lane] = q.x; lq[wv][2 * lane + 1] = q.y;
    __syncthreads();
    int t = threadIdx.x;
    if (t < 128) {
        float ts = ls[0][t] + ls[1][t] + ls[2][t] + ls[3][t];
        float tq = lq[0][t] + lq[1][t] + lq[2][t] + lq[3][t];
        atomicAdd(&sums[t], ts);
        atomicAdd(&sums[128 + t], tq);
    }
}

__global__ void k_bnp(const float* __restrict__ sums, const float* __restrict__ g,
                      const float* __restrict__ be, int N, float* __restrict__ scale,
                      float* __restrict__ shift) {
    int c = threadIdx.x;
    if (c < 128) {
        float invN = 1.0f / (float)N;
        float mu = sums[c] * invN;
        float var = sums[128 + c] * invN - mu * mu;
        var = fmaxf(var, 0.f);
        float s = g[c] * rsqrtf(var + 1e-5f);
        scale[c] = s;
        shift[c] = fmaf(-mu, s, be[c]);
    }
}

// ---------------- Pooling: node-parallel, per-wave run flush (fp16 input) ----------------

__global__ __launch_bounds__(256) void k_pool2(const _Float16* __restrict__ x,
                                               const int* __restrict__ batch,
                                               const float* __restrict__ scale,
                                               const float* __restrict__ shift,
                                               float* __restrict__ psum, int N) {
    int nw = gridDim.x * 4;
    int w = blockIdx.x * 4 + (threadIdx.x >> 6);
    int lane = threadIdx.x & 63;
    int per = (N + nw - 1) / nw;
    int i0 = w * per, i1 = min(N, i0 + per);
    if (i0 >= i1) return;
    const half2_t* b = (const half2_t*)x;
    float2 s2 = ((const float2*)scale)[lane];
    float2 h2 = ((const float2*)shift)[lane];
    float2 acc = make_float2(0.f, 0.f);
    int g = batch[i0];
    for (int i = i0; i < i1; i++) {
        int gi = batch[i];
        if (gi != g) {   // wave-uniform branch
            atomicAdd(&psum[g * 128 + 2 * lane], acc.x);
            atomicAdd(&psum[g * 128 + 2 * lane + 1], acc.y);
            acc = make_float2(0.f, 0.f);
            g = gi;
        }
        half2_t v = b[(size_t)i * 64 + lane];
        acc.x += fmaxf(fmaf((float)v.x, s2.x, h2.x), 0.f);
        acc.y += fmaxf(fmaf((float)v.y, s2.y, h2.y), 0.f);
    }
    atomicAdd(&psum[g * 128 + 2 * lane], acc.x);
    atomicAdd(&psum[g * 128 + 2 * lane + 1], acc.y);
}

// ---------------- Head: out[g][o] = (psum[g]/cnt[g]) @ Wout[:,o] + bout[o] ----------------

__global__ __launch_bounds__(64) void k_final(const float* __restrict__ psum,
                                              const int* __restrict__ gptr,
                                              const float* __restrict__ Wout,
                                              const float* __restrict__ bout,
                                              float* __restrict__ out, int O) {
    int g = blockIdx.x, o = threadIdx.x;
    int cnt = gptr[g + 1] - gptr[g];
    float inv = 1.0f / fmaxf((float)cnt, 1.f);
    float acc = 0.f;
    for (int c = 0; c < 128; c++) acc = fmaf(psum[g * 128 + c], Wout[c * O + o], acc);
    out[g * O + o] = fmaf(acc, inv, bout[o]);
}

// ---------------- Host launch ----------------

extern "C" void kernel_launch(void* const* d_in, const int* in_sizes, int n_in,
                              void* d_out, int out_size, void* d_ws, size_t ws_size,
                              hipStream_t stream) {
    const float* x    = (const float*)d_in[0];
    const int*   edge = (const int*)d_in[1];
    const int*   batch= (const int*)d_in[2];
    const float* W0   = (const float*)d_in[4];
    const float* b0   = (const float*)d_in[5];
    const float* g0   = (const float*)d_in[6];
    const float* be0  = (const float*)d_in[7];
    const float* W1   = (const float*)d_in[8];
    const float* b1   = (const float*)d_in[9];
    const float* g1   = (const float*)d_in[10];
    const float* be1  = (const float*)d_in[11];
    const float* Wout = (const float*)d_in[12];
    const float* bout = (const float*)d_in[13];
    float* out = (float*)d_out;

    const int Hh  = in_sizes[5];              // 128
    const int Fin = in_sizes[4] / Hh;         // 128
    const int N   = in_sizes[0] / Fin;        // 100000
    const int E   = in_sizes[1] / 2;          // 1600000
    const int O   = in_sizes[13];             // 64
    const int G   = out_size / O;             // 128
    (void)Hh; (void)n_in; (void)ws_size;

    // bucket shift: smallest SH >= 8 with <= 512 buckets (pack needs SH <= 9, N < 2^23)
    int SH = 8;
    while (((N + (1 << SH) - 1) >> SH) > 512) SH++;
    const int NBK = (N + (1 << SH) - 1) >> SH;
    const int CH  = ((E + 255) / 256 > 8192) ? (E + 255) / 256 : 8192;  // chunk, keep WG<=256
    const int WG  = (E + CH - 1) / CH;

    char* p = (char*)d_ws;
    auto alloc = [&](size_t bytes) -> void* {
        void* r = (void*)p;
        p += (bytes + 255) & ~(size_t)255;
        return r;
    };
    _Float16* A   = (_Float16*)alloc((size_t)N * 128 * 2);   // fp16 gather table (layer 2)
    _Float16* B   = (_Float16*)alloc((size_t)N * 128 * 2);   // fp16 layer output
    unsigned char* A8 = (unsigned char*)alloc((size_t)N * 128); // fp8 gather table (layer 1)
    float* dinv   = (float*)alloc((size_t)N * 4);
    int*   rp     = (int*)alloc((size_t)(N + 1) * 4);
    int*   colx   = (int*)alloc((size_t)E * 4);
    unsigned* ebuf= (unsigned*)alloc((size_t)E * 4);
    int*   M      = (int*)alloc((size_t)NBK * WG * 4);
    int*   totals = (int*)alloc((size_t)NBK * 4);
    int*   base   = (int*)alloc((size_t)(NBK + 1) * 4);
    float* sums   = (float*)alloc(512 * 4);   // [sum1|sq1|sum2|sq2]
    float* bn     = (float*)alloc(512 * 4);   // [scale1|shift1|scale2|shift2]
    int*   gptr   = (int*)alloc((size_t)(G + 1) * 4);
    float* psum   = (float*)alloc((size_t)G * 128 * 4);
    _Float16* Wt0 = (_Float16*)alloc(128 * 128 * 2);
    _Float16* Wt1 = (_Float16*)alloc(128 * 128 * 2);

    const int* src = edge;
    const int* dst = edge + E;

    // radix-partition CSR build; k_cntfill also does wprep/gptr/psum-zero/sums-zero
    k_hist<<<WG, 256, NBK * 4, stream>>>(dst, E, SH, NBK, WG, CH, M);
    k_colscan<<<NBK, 256, 0, stream>>>(M, WG, totals);
    k_bucketscan<<<1, 512, 0, stream>>>(totals, NBK, E, base);
    k_scatter<<<WG, 256, NBK * 4, stream>>>(src, dst, E, SH, NBK, WG, CH, M, base, ebuf);
    k_cntfill<<<NBK, 256, 0, stream>>>(ebuf, base, SH, N, E, dinv, rp, colx,
                                       W0, W1, Wt0, Wt1, batch, G, gptr, psum, sums);

    // Layer 1 (MFMA GEMM fp32 in, fp8 out -> fp8 gather)
    k_gemmM<<<(N + 63) / 64, 256, 0, stream>>>(x, Wt0, dinv, A8, N);
    k_agg8<<<(N + 3) / 4, 256, 0, stream>>>(A8, rp, colx, dinv, b0, B, N);
    k_stats<<<512, 256, 0, stream>>>(B, N, sums);
    k_bnp<<<1, 128, 0, stream>>>(sums, g0, be0, N, bn, bn + 128);

    // Layer 2 (fp16 in, BN+ReLU fused into MFMA A-frag loads, fp16 gather)
    k_gemmM16<<<(N + 63) / 64, 256, 0, stream>>>(B, Wt1, bn, bn + 128, dinv, A, N);
    k_agg<<<(N + 3) / 4, 256, 0, stream>>>(A, rp, colx, dinv, b1, B, N);
    k_stats<<<512, 256, 0, stream>>>(B, N, sums + 256);
    k_bnp<<<1, 128, 0, stream>>>(sums + 256, g1, be1, N, bn + 256, bn + 384);

    // Pool (BN+ReLU fused) + head (mean division fused)
    k_pool2<<<512, 256, 0, stream>>>(B, batch, bn + 256, bn + 384, psum, N);
    k_final<<<G, 64, 0, stream>>>(psum, gptr, Wout, bout, out, O);
}

// Round 5
// 430.172 us; speedup vs baseline: 1.0341x; 1.0157x over previous
//
#include <hip/hip_runtime.h>
#include <hip/hip_bf16.h>

typedef _Float16 half8_t __attribute__((ext_vector_type(8)));
typedef _Float16 half4_t __attribute__((ext_vector_type(4)));
typedef _Float16 half2_t __attribute__((ext_vector_type(2)));
typedef float float4_t __attribute__((ext_vector_type(4)));

// ---------------- radix-partition CSR build ----------------
// bucket b = dst >> SH (NBK <= 512). Edge chunks of CHUNK per workgroup.
// M[b*WG + w] = #edges of chunk w landing in bucket b; after k_colscan it is
// the per-chunk exclusive offset within bucket b. All hot counters are LDS.

__global__ __launch_bounds__(256) void k_hist(const int* __restrict__ dst, int E, int SH,
                                              int NBK, int WG, int CH, int* __restrict__ M) {
    extern __shared__ int lh[];
    for (int i = threadIdx.x; i < NBK; i += 256) lh[i] = 0;
    __syncthreads();
    int wg = blockIdx.x;
    int e0 = wg * CH, e1 = min(E, e0 + CH);
    for (int e = e0 + threadIdx.x; e < e1; e += 256)
        atomicAdd(&lh[dst[e] >> SH], 1);
    __syncthreads();
    for (int i = threadIdx.x; i < NBK; i += 256) M[i * WG + wg] = lh[i];
}

__global__ __launch_bounds__(256) void k_colscan(int* __restrict__ M, int WG,
                                                 int* __restrict__ totals) {
    __shared__ int s[256];
    int b = blockIdx.x, t = threadIdx.x;
    int v = (t < WG) ? M[b * WG + t] : 0;
    s[t] = v;
    __syncthreads();
    for (int off = 1; off < 256; off <<= 1) {
        int u = (t >= off) ? s[t - off] : 0;
        __syncthreads();
        s[t] += u;
        __syncthreads();
    }
    if (t < WG) M[b * WG + t] = s[t] - v;   // exclusive within bucket
    if (t == 255) totals[b] = s[255];
}

__global__ __launch_bounds__(512) void k_bucketscan(const int* __restrict__ totals, int NBK,
                                                    int E, int* __restrict__ base) {
    __shared__ int s[512];
    int t = threadIdx.x;
    int v = (t < NBK) ? totals[t] : 0;
    s[t] = v;
    __syncthreads();
    for (int off = 1; off < 512; off <<= 1) {
        int u = (t >= off) ? s[t - off] : 0;
        __syncthreads();
        s[t] += u;
        __syncthreads();
    }
    if (t < NBK) base[t] = s[t] - v;
    if (t == 0) base[NBK] = E;
}

// pack: low 23 bits = src node, high 9 bits = dst - (b<<SH). Valid for N < 2^23, SH <= 9.
__global__ __launch_bounds__(256) void k_scatter(const int* __restrict__ src,
                                                 const int* __restrict__ dst, int E, int SH,
                                                 int NBK, int WG, int CH,
                                                 const int* __restrict__ M,
                                                 const int* __restrict__ base,
                                                 unsigned* __restrict__ ebuf) {
    extern __shared__ int cur[];
    int wg = blockIdx.x;
    for (int i = threadIdx.x; i < NBK; i += 256) cur[i] = base[i] + M[i * WG + wg];
    __syncthreads();
    int e0 = wg * CH, e1 = min(E, e0 + CH);
    for (int e = e0 + threadIdx.x; e < e1; e += 256) {
        int d = dst[e];
        int b = d >> SH;
        int pos = atomicAdd(&cur[b], 1);                 // LDS atomic, wg-private
        ebuf[pos] = (unsigned)src[e] | ((unsigned)(d - (b << SH)) << 23);
    }
}

// one wg per bucket: LDS degree histogram -> local pair-scan -> rp/dinv, then
// second ebuf pass writes colx (bucket-local window, LDS cursors).
// Idle-capacity side jobs (consumed only by later dispatches):
//   blocks 0..63:  Wt transpose slices;  block 64: gptr binary search;
//   blocks 65..96: psum zero;            block 97: sums zero + zero-row of A/B.
__global__ __launch_bounds__(256) void k_cntfill(const unsigned* __restrict__ ebuf,
                                                 const int* __restrict__ base, int SH, int N,
                                                 int E, float* __restrict__ dinv,
                                                 int* __restrict__ rp, int* __restrict__ colx,
                                                 const float* __restrict__ W0,
                                                 const float* __restrict__ W1,
                                                 _Float16* __restrict__ Wt0,
                                                 _Float16* __restrict__ Wt1,
                                                 const int* __restrict__ batch, int G,
                                                 int* __restrict__ gptr,
                                                 float* __restrict__ psum,
                                                 float* __restrict__ sums,
                                                 _Float16* __restrict__ A,
                                                 _Float16* __restrict__ B) {
    __shared__ int h[512];
    __shared__ int cur[512];
    __shared__ int s[256];
    int b = blockIdx.x, t = threadIdx.x;

    // side jobs
    if (b < 64) {
        int idx = b * 256 + t;            // 16384 elements over 64 blocks
        int n = idx >> 7, k = idx & 127;
        Wt0[n * 128 + k] = (_Float16)W0[k * 128 + n];
        Wt1[n * 128 + k] = (_Float16)W1[k * 128 + n];
    } else if (b == 64) {
        if (t <= G) {
            int g = t;
            int lo = 0, hi = N;
            while (lo < hi) {
                int mid = (lo + hi) >> 1;
                if (batch[mid] < g) lo = mid + 1; else hi = mid;
            }
            gptr[g] = lo;
        }
    } else if (b < 97) {
        int i0 = (b - 65) * 512 + t;      // G*128 = 16384 floats over 32 blocks
        psum[i0] = 0.f;
        psum[i0 + 256] = 0.f;
    } else if (b == 97) {
        if (t < 256) { sums[t] = 0.f; sums[t + 256] = 0.f; }
        // zero row at index N of both gather tables (predication target)
        if (t < 128) {
            A[(size_t)N * 128 + t] = (_Float16)0.f;
            B[(size_t)N * 128 + t] = (_Float16)0.f;
        }
    }

    // main cntfill work
    int n0 = b << SH;
    int nb = min(N - n0, 1 << SH);
    for (int i = t; i < nb; i += 256) h[i] = 0;
    __syncthreads();
    int e0 = base[b], e1 = base[b + 1];
    for (int e = e0 + t; e < e1; e += 256)
        atomicAdd(&h[ebuf[e] >> 23], 1);
    __syncthreads();
    int i0 = 2 * t, i1 = 2 * t + 1;
    int a0 = (i0 < nb) ? h[i0] : 0;
    int a1 = (i1 < nb) ? h[i1] : 0;
    int ps = a0 + a1;
    s[t] = ps;
    __syncthreads();
    for (int off = 1; off < 256; off <<= 1) {
        int u = (t >= off) ? s[t - off] : 0;
        __syncthreads();
        s[t] += u;
        __syncthreads();
    }
    int excl = s[t] - ps;
    if (i0 < nb) {
        int r0 = e0 + excl;
        cur[i0] = r0;
        rp[n0 + i0] = r0;
        dinv[n0 + i0] = rsqrtf((float)(a0 + 1));
    }
    if (i1 < nb) {
        int r1 = e0 + excl + a0;
        cur[i1] = r1;
        rp[n0 + i1] = r1;
        dinv[n0 + i1] = rsqrtf((float)(a1 + 1));
    }
    if (b == (int)gridDim.x - 1 && t == 0) rp[N] = E;
    __syncthreads();
    for (int e = e0 + t; e < e1; e += 256) {
        unsigned v = ebuf[e];
        int pos = atomicAdd(&cur[v >> 23], 1);           // LDS atomic, wg-private
        colx[pos] = (int)(v & 0x7FFFFFu);
    }
}

// ---------------- MFMA GEMM: out[row] = (X[row] @ W) * dinv[row] (fp16 out) ----------------
// 4 waves/block, 16 rows/wave. A-frags direct from global; B = half8 from
// L1/L2-resident Wt[n][k]. C/D: col=lane&15, row=quad*4+reg.

__global__ __launch_bounds__(256) void k_gemmM(const float* __restrict__ X,
                                               const _Float16* __restrict__ Wt,
                                               const float* __restrict__ dinv,
                                               _Float16* __restrict__ out, int N) {
    int t = threadIdx.x;
    int wv = t >> 6, lane = t & 63;
    int m = lane & 15, quad = lane >> 4;
    int rowbase = blockIdx.x * 64 + wv * 16;
    int arow = rowbase + m;
    int arowc = (arow < N) ? arow : (N - 1);
    const float* xr = X + (size_t)arowc * 128;

    float4_t acc[8];
    #pragma unroll
    for (int i = 0; i < 8; i++) acc[i] = (float4_t){0.f, 0.f, 0.f, 0.f};

    #pragma unroll
    for (int kc = 0; kc < 4; kc++) {
        int k0 = kc * 32 + quad * 8;
        float4 xa = *(const float4*)(xr + k0);
        float4 xb = *(const float4*)(xr + k0 + 4);
        float xv[8] = {xa.x, xa.y, xa.z, xa.w, xb.x, xb.y, xb.z, xb.w};
        half8_t a;
        #pragma unroll
        for (int j = 0; j < 8; j++) a[j] = (_Float16)xv[j];
        #pragma unroll
        for (int nt = 0; nt < 8; nt++) {
            half8_t b = *(const half8_t*)(Wt + (size_t)(nt * 16 + m) * 128 + k0);
            acc[nt] = __builtin_amdgcn_mfma_f32_16x16x32_f16(a, b, acc[nt], 0, 0, 0);
        }
    }

    float dv[4];
    #pragma unroll
    for (int r = 0; r < 4; r++) {
        int row = rowbase + quad * 4 + r;
        dv[r] = dinv[(row < N) ? row : (N - 1)];
    }
    #pragma unroll
    for (int r = 0; r < 4; r++) {
        int row = rowbase + quad * 4 + r;
        if (row < N) {
            _Float16* o = out + (size_t)row * 128 + m;
            #pragma unroll
            for (int nt = 0; nt < 8; nt++)
                o[nt * 16] = (_Float16)(acc[nt][r] * dv[r]);
        }
    }
}

// fp16-input variant, layer 2: BN params computed per-block from sums (bnp
// fused away), BN+ReLU applied in A-frag loads.
__global__ __launch_bounds__(256) void k_gemmM16(const _Float16* __restrict__ X,
                                                 const _Float16* __restrict__ Wt,
                                                 const float* __restrict__ sums,
                                                 const float* __restrict__ g,
                                                 const float* __restrict__ be,
                                                 const float* __restrict__ dinv,
                                                 _Float16* __restrict__ out, int N) {
    __shared__ alignas(16) float ss[128];
    __shared__ alignas(16) float hh[128];
    int t = threadIdx.x;
    if (t < 128) {
        float invN = 1.0f / (float)N;
        float mu = sums[t] * invN;
        float var = fmaxf(sums[128 + t] * invN - mu * mu, 0.f);
        float sc = g[t] * rsqrtf(var + 1e-5f);
        ss[t] = sc;
        hh[t] = fmaf(-mu, sc, be[t]);
    }
    __syncthreads();

    int wv = t >> 6, lane = t & 63;
    int m = lane & 15, quad = lane >> 4;
    int rowbase = blockIdx.x * 64 + wv * 16;
    int arow = rowbase + m;
    int arowc = (arow < N) ? arow : (N - 1);
    const _Float16* xr = X + (size_t)arowc * 128;

    float4_t acc[8];
    #pragma unroll
    for (int i = 0; i < 8; i++) acc[i] = (float4_t){0.f, 0.f, 0.f, 0.f};

    #pragma unroll
    for (int kc = 0; kc < 4; kc++) {
        int k0 = kc * 32 + quad * 8;
        half8_t x8 = *(const half8_t*)(xr + k0);
        float4 sa = *(const float4*)(ss + k0);
        float4 sb = *(const float4*)(ss + k0 + 4);
        float4 ha = *(const float4*)(hh + k0);
        float4 hb = *(const float4*)(hh + k0 + 4);
        float sv[8] = {sa.x, sa.y, sa.z, sa.w, sb.x, sb.y, sb.z, sb.w};
        float hv[8] = {ha.x, ha.y, ha.z, ha.w, hb.x, hb.y, hb.z, hb.w};
        half8_t a;
        #pragma unroll
        for (int j = 0; j < 8; j++)
            a[j] = (_Float16)fmaxf(fmaf((float)x8[j], sv[j], hv[j]), 0.f);
        #pragma unroll
        for (int nt = 0; nt < 8; nt++) {
            half8_t b = *(const half8_t*)(Wt + (size_t)(nt * 16 + m) * 128 + k0);
            acc[nt] = __builtin_amdgcn_mfma_f32_16x16x32_f16(a, b, acc[nt], 0, 0, 0);
        }
    }

    float dv[4];
    #pragma unroll
    for (int r = 0; r < 4; r++) {
        int row = rowbase + quad * 4 + r;
        dv[r] = dinv[(row < N) ? row : (N - 1)];
    }
    #pragma unroll
    for (int r = 0; r < 4; r++) {
        int row = rowbase + quad * 4 + r;
        if (row < N) {
            _Float16* o = out + (size_t)row * 128 + m;
            #pragma unroll
            for (int nt = 0; nt < 8; nt++)
                o[nt * 16] = (_Float16)(acc[nt][r] * dv[r]);
        }
    }
}

// ---------------- Aggregation: out[i] = dinv[i]*(hs[i] + sum_{j in in(i)} hs[j]) + b ----------------
// One wave per node, quarter-wave row reads (16 lanes x half8 = 256B row),
// 4 independent edge streams, one predicated batch of 8 slots/quarter for
// deg<=32. Invalid slots gather the ZERO ROW (index N) -> no weights, and the
// accumulate is packed fp16 (v_pk_add_f16, 4 ops per 8-ch slot) instead of
// scalar cvt+fma (16 ops) -- the VALU pipe was the top consumer (55% busy).
// Per-quarter partials sum <=8 fp16 values; reduce + epilogue stay f32.

__global__ __launch_bounds__(256) void k_agg(const _Float16* __restrict__ hs,
                                             const int* __restrict__ rp,
                                             const int* __restrict__ colx,
                                             const float* __restrict__ dinv,
                                             const float* __restrict__ bias,
                                             _Float16* __restrict__ out, int N) {
    int wave = (blockIdx.x * 256 + threadIdx.x) >> 6;
    int lane = threadIdx.x & 63;
    if (wave >= N) return;
    int i = wave;
    int q = lane >> 4;            // quarter 0..3: independent edge stream
    int c8 = lane & 15;           // channels 8*c8 .. 8*c8+7
    const half8_t* row8 = (const half8_t*)hs;

    half8_t sv = row8[(size_t)i * 16 + c8];   // self row, issued early
    int k0 = rp[i], k1 = rp[i + 1];
    int deg = k1 - k0;

    half8_t a8 = {};

    if (deg <= 32) {
        int j[8];
        #pragma unroll
        for (int s2 = 0; s2 < 8; s2++) {
            int kk = k0 + q + 4 * s2;
            int jl = colx[kk];            // may read past k1 into ws (mapped); discarded
            j[s2] = (kk < k1) ? jl : N;   // invalid slots -> zero row
        }
        half8_t v[8];
        #pragma unroll
        for (int s2 = 0; s2 < 8; s2++)
            v[s2] = row8[(size_t)j[s2] * 16 + c8];
        #pragma unroll
        for (int s2 = 0; s2 < 8; s2++)
            a8 += v[s2];                  // 4x v_pk_add_f16
    } else {
        int k = k0 + q;
        for (; k + 12 < k1; k += 16) {
            int j0 = colx[k];
            int j1 = colx[k + 4];
            int j2 = colx[k + 8];
            int j3 = colx[k + 12];
            half8_t v0 = row8[(size_t)j0 * 16 + c8];
            half8_t v1 = row8[(size_t)j1 * 16 + c8];
            half8_t v2 = row8[(size_t)j2 * 16 + c8];
            half8_t v3 = row8[(size_t)j3 * 16 + c8];
            a8 += v0; a8 += v1; a8 += v2; a8 += v3;
        }
        for (; k < k1; k += 4) {
            int jj = colx[k];
            a8 += row8[(size_t)jj * 16 + c8];
        }
    }

    // f32 from here: cross-quarter reduce over lanes {l, l+16, l+32, l+48}
    float a[8];
    #pragma unroll
    for (int t = 0; t < 8; t++) a[t] = (float)a8[t];
    #pragma unroll
    for (int t = 0; t < 8; t++) {
        float x = a[t];
        x += __shfl_xor(x, 16);
        x += __shfl_xor(x, 32);
        a[t] = x;
    }

    if (q == 0) {
        float d = dinv[i];
        float4 bA = ((const float4*)bias)[2 * c8];
        float4 bB = ((const float4*)bias)[2 * c8 + 1];
        float bb[8] = {bA.x, bA.y, bA.z, bA.w, bB.x, bB.y, bB.z, bB.w};
        half8_t o;
        #pragma unroll
        for (int t = 0; t < 8; t++)
            o[t] = (_Float16)fmaf(a[t] + (float)sv[t], d, bb[t]);
        ((half8_t*)out)[(size_t)i * 16 + c8] = o;
    }
}

// ---------------- BN stats (fp16 input) ----------------

__global__ __launch_bounds__(256) void k_stats(const _Float16* __restrict__ x, int N,
                                               float* __restrict__ sums) {
    int lane = threadIdx.x & 63;
    int wv = threadIdx.x >> 6;
    int gw = blockIdx.x * 4 + wv;
    int stride = gridDim.x * 4;
    const half2_t* b = (const half2_t*)x;
    float2 s = make_float2(0.f, 0.f), q = make_float2(0.f, 0.f);
    for (int i = gw; i < N; i += stride) {
        half2_t v = b[(size_t)i * 64 + lane];
        float vx = (float)v.x, vy = (float)v.y;
        s.x += vx; s.y += vy;
        q.x += vx * vx; q.y += vy * vy;
    }
    __shared__ float ls[4][128];
    __shared__ float lq[4][128];
    ls[wv][2 * lane] = s.x; ls[wv][2 * lane + 1] = s.y;
    lq[wv][2 * lane] = q.x; lq[wv][2 * lane + 1] = q.y;
    __syncthreads();
    int t = threadIdx.x;
    if (t < 128) {
        float ts = ls[0][t] + ls[1][t] + ls[2][t] + ls[3][t];
        float tq = lq[0][t] + lq[1][t] + lq[2][t] + lq[3][t];
        atomicAdd(&sums[t], ts);
        atomicAdd(&sums[128 + t], tq);
    }
}

// ---------------- Pooling: node-parallel, per-wave run flush (fp16 input) ----------------
// BN2 params computed per-block from sums (bnp fused away).

__global__ __launch_bounds__(256) void k_pool2(const _Float16* __restrict__ x,
                                               const int* __restrict__ batch,
                                               const float* __restrict__ sums,
                                               const float* __restrict__ g2,
                                               const float* __restrict__ be2,
                                               float* __restrict__ psum, int N) {
    __shared__ alignas(8) float ss[128];
    __shared__ alignas(8) float hh[128];
    int t = threadIdx.x;
    if (t < 128) {
        float invN = 1.0f / (float)N;
        float mu = sums[t] * invN;
        float var = fmaxf(sums[128 + t] * invN - mu * mu, 0.f);
        float sc = g2[t] * rsqrtf(var + 1e-5f);
        ss[t] = sc;
        hh[t] = fmaf(-mu, sc, be2[t]);
    }
    __syncthreads();

    int nw = gridDim.x * 4;
    int w = blockIdx.x * 4 + (threadIdx.x >> 6);
    int lane = threadIdx.x & 63;
    int per = (N + nw - 1) / nw;
    int i0 = w * per, i1 = min(N, i0 + per);
    if (i0 >= i1) return;
    const half2_t* b = (const half2_t*)x;
    float2 s2 = ((const float2*)ss)[lane];
    float2 h2 = ((const float2*)hh)[lane];
    float2 acc = make_float2(0.f, 0.f);
    int g = batch[i0];
    for (int i = i0; i < i1; i++) {
        int gi = batch[i];
        if (gi != g) {   // wave-uniform branch
            atomicAdd(&psum[g * 128 + 2 * lane], acc.x);
            atomicAdd(&psum[g * 128 + 2 * lane + 1], acc.y);
            acc = make_float2(0.f, 0.f);
            g = gi;
        }
        half2_t v = b[(size_t)i * 64 + lane];
        acc.x += fmaxf(fmaf((float)v.x, s2.x, h2.x), 0.f);
        acc.y += fmaxf(fmaf((float)v.y, s2.y, h2.y), 0.f);
    }
    atomicAdd(&psum[g * 128 + 2 * lane], acc.x);
    atomicAdd(&psum[g * 128 + 2 * lane + 1], acc.y);
}

// ---------------- Head: out[g][o] = (psum[g]/cnt[g]) @ Wout[:,o] + bout[o] ----------------

__global__ __launch_bounds__(64) void k_final(const float* __restrict__ psum,
                                              const int* __restrict__ gptr,
                                              const float* __restrict__ Wout,
                                              const float* __restrict__ bout,
                                              float* __restrict__ out, int O) {
    int g = blockIdx.x, o = threadIdx.x;
    int cnt = gptr[g + 1] - gptr[g];
    float inv = 1.0f / fmaxf((float)cnt, 1.f);
    float acc = 0.f;
    for (int c = 0; c < 128; c++) acc = fmaf(psum[g * 128 + c], Wout[c * O + o], acc);
    out[g * O + o] = fmaf(acc, inv, bout[o]);
}

// ---------------- Host launch ----------------

extern "C" void kernel_launch(void* const* d_in, const int* in_sizes, int n_in,
                              void* d_out, int out_size, void* d_ws, size_t ws_size,
                              hipStream_t stream) {
    const float* x    = (const float*)d_in[0];
    const int*   edge = (const int*)d_in[1];
    const int*   batch= (const int*)d_in[2];
    const float* W0   = (const float*)d_in[4];
    const float* b0   = (const float*)d_in[5];
    const float* g0   = (const float*)d_in[6];
    const float* be0  = (const float*)d_in[7];
    const float* W1   = (const float*)d_in[8];
    const float* b1   = (const float*)d_in[9];
    const float* g1   = (const float*)d_in[10];
    const float* be1  = (const float*)d_in[11];
    const float* Wout = (const float*)d_in[12];
    const float* bout = (const float*)d_in[13];
    float* out = (float*)d_out;

    const int Hh  = in_sizes[5];              // 128
    const int Fin = in_sizes[4] / Hh;         // 128
    const int N   = in_sizes[0] / Fin;        // 100000
    const int E   = in_sizes[1] / 2;          // 1600000
    const int O   = in_sizes[13];             // 64
    const int G   = out_size / O;             // 128
    (void)Hh; (void)n_in; (void)ws_size;

    // bucket shift: smallest SH >= 8 with <= 512 buckets (pack needs SH <= 9, N < 2^23)
    int SH = 8;
    while (((N + (1 << SH) - 1) >> SH) > 512) SH++;
    const int NBK = (N + (1 << SH) - 1) >> SH;
    const int CH  = ((E + 255) / 256 > 8192) ? (E + 255) / 256 : 8192;  // chunk, keep WG<=256
    const int WG  = (E + CH - 1) / CH;

    char* p = (char*)d_ws;
    auto alloc = [&](size_t bytes) -> void* {
        void* r = (void*)p;
        p += (bytes + 255) & ~(size_t)255;
        return r;
    };
    _Float16* A   = (_Float16*)alloc((size_t)(N + 1) * 128 * 2);  // fp16 gather table + zero row
    _Float16* B   = (_Float16*)alloc((size_t)(N + 1) * 128 * 2);  // fp16 layer output + zero row
    float* dinv   = (float*)alloc((size_t)N * 4);
    int*   rp     = (int*)alloc((size_t)(N + 1) * 4);
    int*   colx   = (int*)alloc((size_t)E * 4);
    unsigned* ebuf= (unsigned*)alloc((size_t)E * 4);
    int*   M      = (int*)alloc((size_t)NBK * WG * 4);
    int*   totals = (int*)alloc((size_t)NBK * 4);
    int*   base   = (int*)alloc((size_t)(NBK + 1) * 4);
    float* sums   = (float*)alloc(512 * 4);   // [sum1|sq1|sum2|sq2]
    int*   gptr   = (int*)alloc((size_t)(G + 1) * 4);
    float* psum   = (float*)alloc((size_t)G * 128 * 4);
    _Float16* Wt0 = (_Float16*)alloc(128 * 128 * 2);
    _Float16* Wt1 = (_Float16*)alloc(128 * 128 * 2);

    const int* src = edge;
    const int* dst = edge + E;

    // radix-partition CSR build; k_cntfill also does wprep/gptr/psum-zero/sums-zero/zero-rows
    k_hist<<<WG, 256, NBK * 4, stream>>>(dst, E, SH, NBK, WG, CH, M);
    k_colscan<<<NBK, 256, 0, stream>>>(M, WG, totals);
    k_bucketscan<<<1, 512, 0, stream>>>(totals, NBK, E, base);
    k_scatter<<<WG, 256, NBK * 4, stream>>>(src, dst, E, SH, NBK, WG, CH, M, base, ebuf);
    k_cntfill<<<NBK, 256, 0, stream>>>(ebuf, base, SH, N, E, dinv, rp, colx,
                                       W0, W1, Wt0, Wt1, batch, G, gptr, psum, sums, A, B);

    // Layer 1 (MFMA GEMM fp32 in, fp16 out)
    k_gemmM<<<(N + 63) / 64, 256, 0, stream>>>(x, Wt0, dinv, A, N);
    k_agg<<<(N + 3) / 4, 256, 0, stream>>>(A, rp, colx, dinv, b0, B, N);
    k_stats<<<512, 256, 0, stream>>>(B, N, sums);

    // Layer 2 (fp16 in, BN1 params computed in-kernel, BN+ReLU fused into A-frags)
    k_gemmM16<<<(N + 63) / 64, 256, 0, stream>>>(B, Wt1, sums, g0, be0, dinv, A, N);
    k_agg<<<(N + 3) / 4, 256, 0, stream>>>(A, rp, colx, dinv, b1, B, N);
    k_stats<<<512, 256, 0, stream>>>(B, N, sums + 256);

    // Pool (BN2 computed in-kernel, BN+ReLU fused) + head (mean division fused)
    k_pool2<<<512, 256, 0, stream>>>(B, batch, sums + 256, g1, be1, psum, N);
    k_final<<<G, 64, 0, stream>>>(psum, gptr, Wout, bout, out, O);
}